// Round 9
// baseline (464.644 us; speedup 1.0000x reference)
//
#include <hip/hip_runtime.h>

typedef __attribute__((ext_vector_type(4))) float  f32x4;
typedef __attribute__((ext_vector_type(2))) float  f32x2;
typedef __attribute__((ext_vector_type(8))) short  s16x8;
typedef __attribute__((ext_vector_type(4))) float  f4v;
typedef __attribute__((ext_vector_type(4))) int    i32x4;

#define MFMA_BF16 __builtin_amdgcn_mfma_f32_16x16x32_bf16
#define SENT 0x7fffffff

#if defined(__has_builtin)
#if __has_builtin(__builtin_amdgcn_cvt_pk_fp8_f32) && __has_builtin(__builtin_amdgcn_cvt_pk_f32_fp8)
#define HW8 1
#endif
#endif

// ---------- helpers ----------
__device__ __forceinline__ short f2bf(float f) {
  unsigned u = __builtin_bit_cast(unsigned, f);
  u += 0x7fffu + ((u >> 16) & 1u);
  return (short)(u >> 16);
}
__device__ __forceinline__ float bf2f(short s) {
  unsigned u = ((unsigned)(unsigned short)s) << 16;
  return __builtin_bit_cast(float, u);
}
__device__ __forceinline__ s16x8 cvt8(f4v f0, f4v f1) {
  s16x8 r;
  r[0] = f2bf(f0[0]); r[1] = f2bf(f0[1]); r[2] = f2bf(f0[2]); r[3] = f2bf(f0[3]);
  r[4] = f2bf(f1[0]); r[5] = f2bf(f1[1]); r[6] = f2bf(f1[2]); r[7] = f2bf(f1[3]);
  return r;
}
// HW packed bf16 convert (gfx950)
__device__ __forceinline__ unsigned cvtpk_bf16(float a, float b) {
  unsigned r;
  asm("v_cvt_pk_bf16_f32 %0, %1, %2" : "=v"(r) : "v"(a), "v"(b));
  return r;
}
// manual fp8 e4m3fn (fallback when no HW builtin)
__device__ __forceinline__ unsigned f2fp8(float x) {
  unsigned u = __builtin_bit_cast(unsigned, x);
  unsigned s = (u >> 24) & 0x80u;
  unsigned au = u & 0x7fffffffu;
  if (au < 0x3C800000u) return s;
  unsigned biased = au - 0x3C000000u;
  unsigned val = biased >> 20;
  unsigned rem = biased & 0xFFFFFu;
  val += (rem > 0x80000u) || (rem == 0x80000u && (val & 1u));
  if (val > 0x7Eu) val = 0x7Eu;
  return s | val;
}
__device__ __forceinline__ float fp8tof(unsigned b) {
  unsigned em = b & 0x7fu;
  unsigned f = ((em + 960u) << 20) | ((b & 0x80u) << 24);
  return (em < 8u) ? 0.f : __builtin_bit_cast(float, f);
}
__device__ __forceinline__ unsigned char enc_fp8(float x) {
#ifdef HW8
  return (unsigned char)(__builtin_amdgcn_cvt_pk_fp8_f32(x, x, 0u, false) & 0xffu);
#else
  return (unsigned char)f2fp8(x);
#endif
}
__device__ __forceinline__ void dec_fp8x4(unsigned d, float* f) {
#ifdef HW8
  f32x2 lo = __builtin_amdgcn_cvt_pk_f32_fp8(d, false);
  f32x2 hi = __builtin_amdgcn_cvt_pk_f32_fp8(d, true);
  f[0] = lo[0]; f[1] = lo[1]; f[2] = hi[0]; f[3] = hi[1];
#else
#pragma unroll
  for (int j = 0; j < 4; ++j) f[j] = fp8tof((d >> (8 * j)) & 0xffu);
#endif
}

// ---------- weight prep (r4 verified) ----------
__global__ __launch_bounds__(256) void prep_weights(
    const float* __restrict__ W1, const float* __restrict__ W2,
    short* __restrict__ wp) {
  int t = blockIdx.x * 256 + threadIdx.x;
  int chunk = t >> 6, l = t & 63;
  if (chunk >= 104) return;
  int q = l >> 4, c = l & 15;
  s16x8 v;
  if (chunk < 72) {
    int kk = chunk >> 3, nt = chunk & 7;
    int k0 = kk * 32 + q * 8, n = nt * 16 + c;
#pragma unroll
    for (int j = 0; j < 8; ++j) {
      int k = k0 + j;
      v[j] = (k < 272) ? f2bf(W1[k * 128 + n]) : (short)0;
    }
    *reinterpret_cast<s16x8*>(wp + (size_t)chunk * 512 + l * 8) = v;
  } else {
    int c2 = chunk - 72;
    int kk = c2 >> 3, nt = c2 & 7;
    int k0 = kk * 32 + q * 8, n = nt * 16 + c;
#pragma unroll
    for (int j = 0; j < 8; ++j) v[j] = f2bf(W2[(k0 + j) * 128 + n]);
    *reinterpret_cast<s16x8*>(wp + 36864 + (size_t)c2 * 512 + l * 8) = v;
  }
}

// ---------- fused dense G + edge histogram (r4 verified) ----------
// G layout per node: 384 B = [128 bf16 G1 (row half)] [128 B fp8 G2 (col half, permuted)]
#define NB_H 512
__global__ __launch_bounds__(256) void k_gh(
    const float* __restrict__ h, const short* __restrict__ wp,
    short* __restrict__ Gs, const int* __restrict__ ei,
    int* __restrict__ cnt, int NN, int NB_G, int E) {
  if ((int)blockIdx.x >= NB_G) {
    int i = ((int)blockIdx.x - NB_G) * 256 + threadIdx.x;
    for (; i < E; i += NB_H * 256) atomicAdd(&cnt[ei[i]], 1);
    return;
  }
  const int tid = threadIdx.x;
  const int w = tid >> 6, l = tid & 63;
  const int q = l >> 4, c = l & 15;
  const int nb = blockIdx.x * 64 + w * 16;

  f32x4 acc[16];
#pragma unroll
  for (int nt = 0; nt < 16; ++nt) acc[nt] = (f32x4){0.f, 0.f, 0.f, 0.f};

#pragma unroll
  for (int kk = 0; kk < 4; ++kk) {
    int node = nb + c; if (node >= NN) node = NN - 1;
    const float* src = h + (size_t)node * 128 + kk * 32 + q * 8;
    s16x8 a = cvt8(*reinterpret_cast<const f4v*>(src),
                   *reinterpret_cast<const f4v*>(src + 4));
#pragma unroll
    for (int nt2 = 0; nt2 < 16; ++nt2) {
      int kkg = kk + ((nt2 >= 8) ? 4 : 0);
      int chunk = kkg * 8 + (nt2 & 7);
      s16x8 b = *reinterpret_cast<const s16x8*>(wp + (size_t)chunk * 512 + l * 8);
      acc[nt2] = MFMA_BF16(a, b, acc[nt2], 0, 0, 0);
    }
  }
  unsigned char* Gb = (unsigned char*)Gs;
#pragma unroll
  for (int nt2 = 0; nt2 < 16; ++nt2)
#pragma unroll
    for (int r = 0; r < 4; ++r) {
      int node = nb + q * 4 + r;
      if (node < NN) {
        if (nt2 < 8) {
          Gs[(size_t)node * 192 + nt2 * 16 + c] = f2bf(acc[nt2][r]);
        } else {
          int n7 = nt2 - 8;
          int addr = ((n7 & 1) * 2 + (c >> 3)) * 32 + (n7 >> 1) * 8 + (c & 7);
          Gb[(size_t)node * 384 + 256 + addr] = enc_fp8(acc[nt2][r]);
        }
      }
    }
}

// ---------- 3-phase exclusive scan (r4 verified) ----------
__global__ __launch_bounds__(1024) void k_s1(const int* __restrict__ cnt,
                                             int* __restrict__ partial, int NN) {
  __shared__ int red[16];
  int t = threadIdx.x, idx = blockIdx.x * 1024 + t;
  int v = (idx < NN) ? cnt[idx] : 0;
#pragma unroll
  for (int d = 1; d < 64; d <<= 1) v += __shfl_xor(v, d);
  if ((t & 63) == 0) red[t >> 6] = v;
  __syncthreads();
  if (t == 0) {
    int s = 0;
#pragma unroll
    for (int i = 0; i < 16; ++i) s += red[i];
    partial[blockIdx.x] = s;
  }
}
__global__ __launch_bounds__(1024) void k_s2(int* __restrict__ partial, int P) {
  __shared__ int ps[1024];
  int t = threadIdx.x;
  int v = (t < P) ? partial[t] : 0;
  ps[t] = v; __syncthreads();
  for (int d = 1; d < 1024; d <<= 1) {
    int u = (t >= d) ? ps[t - d] : 0;
    __syncthreads(); ps[t] += u; __syncthreads();
  }
  if (t < P) partial[t] = ps[t] - v;
}
__global__ __launch_bounds__(1024) void k_s3(int* __restrict__ cnt,
                                             const int* __restrict__ partial, int NN) {
  __shared__ int ps[1024];
  int t = threadIdx.x, idx = blockIdx.x * 1024 + t;
  int v = (idx < NN) ? cnt[idx] : 0;
  ps[t] = v; __syncthreads();
  for (int d = 1; d < 1024; d <<= 1) {
    int u = (t >= d) ? ps[t - d] : 0;
    __syncthreads(); ps[t] += u; __syncthreads();
  }
  if (idx < NN) cnt[idx] = ps[t] - v + partial[blockIdx.x];
}

// ---------- scatter v8: sorted (row|col) + sorted bf16 bond data (r8 verified) ----------
__global__ void k_scatter8(const int* __restrict__ ei, int* __restrict__ cnt,
                           int* __restrict__ rc, short* __restrict__ bond_s,
                           const float* __restrict__ bond, int E) {
  int i = blockIdx.x * blockDim.x + threadIdx.x;
  int stride = gridDim.x * blockDim.x;
  for (; i < E; i += stride) {
    int r = ei[i], c = ei[(size_t)E + i];
    int pos = atomicAdd(&cnt[r], 1);
    rc[pos] = r | (c << 16);
    const f4v* b4 = reinterpret_cast<const f4v*>(bond + (size_t)i * 16);
    s16x8 lo = cvt8(b4[0], b4[1]);
    s16x8 hi = cvt8(b4[2], b4[3]);
    s16x8* dst = reinterpret_cast<s16x8*>(bond_s + (size_t)pos * 16);
    dst[0] = lo;
    dst[1] = hi;
  }
}

// ---------- scatter v7 (fallback path) ----------
__global__ void k_scatter(const int* __restrict__ ei, int* __restrict__ cnt,
                          int2* __restrict__ rce, int E) {
  int i = blockIdx.x * blockDim.x + threadIdx.x;
  int stride = gridDim.x * blockDim.x;
  for (; i < E; i += stride) {
    int r = ei[i], c = ei[(size_t)E + i];
    int pos = atomicAdd(&cnt[r], 1);
    rce[pos] = make_int2(r | (c << 16), i);
  }
}

// ---------- fused edge kernel v9: 2-group ILP (all gathers hoisted) ----------
// 256 thr = 4 waves; each wave owns TWO independent 16-edge groups (128 edges/block).
// All 14 gather instructions (both groups) issue before any compute: group 1's
// ~500-cycle gather latency hides entirely under group 0's MFMA/silu pipeline.
__global__ __launch_bounds__(256, 4) void edge_mlp9(
    const short* __restrict__ Gs, const int* __restrict__ rc,
    const short* __restrict__ bond_s, const short* __restrict__ wp,
    const float* __restrict__ b1, const float* __restrict__ b2,
    float* __restrict__ out, int E) {
  __shared__ __align__(16) char ubuf[4 * 16 * 136 * 2];   // Plds/Sred union, wave-private
  short (*Plds)[16][136] = reinterpret_cast<short(*)[16][136]>(ubuf);
  float (*Sred)[16][68]  = reinterpret_cast<float(*)[16][68]>(ubuf);
  __shared__ int rows_s[128];
  __shared__ int cols_s[128];

  const int tid = threadIdx.x;
  const int w = tid >> 6, l = tid & 63;
  const int q = l >> 4, c = l & 15;

  // XCD-chunked bijective swizzle
  int nwg = gridDim.x;
  int qq = nwg >> 3, rr = nwg & 7;
  int xcd = blockIdx.x & 7, idx = blockIdx.x >> 3;
  int sbid = (xcd < rr ? xcd * (qq + 1) : rr * (qq + 1) + (xcd - rr) * qq) + idx;
  const int eb = sbid * 128;

  if (tid < 128) {
    int gpos = eb + tid;
    if (gpos < E) {
      int v = rc[gpos];
      rows_s[tid] = v & 0xffff;
      cols_s[tid] = ((unsigned)v) >> 16;
    } else {
      rows_s[tid] = SENT; cols_s[tid] = 0;
    }
  }
  __syncthreads();

  const int we = w * 16;
  int rA[2], cA[2];
  unsigned long long bm[2];
#pragma unroll
  for (int g = 0; g < 2; ++g) {
    int el = g * 64 + we + c;
    int rv = rows_s[el];
    rA[g] = (rv == SENT) ? 0 : rv;
    cA[g] = cols_s[el];
    bm[g] = __ballot(
        (l < 16) &&
        (rows_s[g * 64 + we + l] != ((l < 15) ? rows_s[g * 64 + we + l + 1] : -1)));
  }

  // ---- issue ALL gathers (both groups) before any compute ----
  s16x8 g1v[2][4];
  i32x4 g2v[2][2];
  s16x8 az[2];
#pragma unroll
  for (int g = 0; g < 2; ++g) {
    const short* gb = Gs + (size_t)rA[g] * 192;
#pragma unroll
    for (int kk = 0; kk < 4; ++kk)
      g1v[g][kk] = *reinterpret_cast<const s16x8*>(gb + kk * 32 + q * 8);
    const char* g2b = (const char*)Gs + (size_t)cA[g] * 384 + 256 + q * 32;
    g2v[g][0] = *reinterpret_cast<const i32x4*>(g2b);
    g2v[g][1] = *reinterpret_cast<const i32x4*>(g2b + 16);
    s16x8 a0 = {};
    if (q < 2) {
      int ge = eb + g * 64 + we + c; if (ge >= E) ge = E - 1;
      a0 = *reinterpret_cast<const s16x8*>(bond_s + (size_t)ge * 16 + q * 8);
    }
    az[g] = a0;
  }

  // ---- process groups sequentially (registers reused; gathers already in flight) ----
#pragma unroll
  for (int g = 0; g < 2; ++g) {
    if (g) __syncthreads();   // keep waves in lockstep between groups (matches v8 cadence)

    // bond @ W1c (MFMA)
    f32x4 accb[8];
#pragma unroll
    for (int nt = 0; nt < 8; ++nt) accb[nt] = (f32x4){0.f, 0.f, 0.f, 0.f};
#pragma unroll
    for (int nt = 0; nt < 8; ++nt) {
      s16x8 b = *reinterpret_cast<const s16x8*>(wp + (size_t)(64 + nt) * 512 + l * 8);
      accb[nt] = MFMA_BF16(az[g], b, accb[nt], 0, 0, 0);
    }

    // bridge C->A through LDS, fold b1 (wave-private, dataflow-ordered)
#pragma unroll
    for (int nt = 0; nt < 8; ++nt) {
      float bias = b1[nt * 16 + c];
#pragma unroll
      for (int r = 0; r < 4; ++r)
        Plds[w][q * 4 + r][nt * 16 + c] = f2bf(accb[nt][r] + bias);
    }

    // GEMM2: A = silu(g1 + g2 + bondterm), packed via v_cvt_pk_bf16_f32
    f32x4 acc2[8];
#pragma unroll
    for (int nt = 0; nt < 8; ++nt) acc2[nt] = (f32x4){0.f, 0.f, 0.f, 0.f};

#pragma unroll
    for (int kk = 0; kk < 4; ++kk) {
      s16x8 gk = g1v[g][kk];
      unsigned d0 = (unsigned)g2v[g][kk >> 1][(kk & 1) * 2 + 0];
      unsigned d1 = (unsigned)g2v[g][kk >> 1][(kk & 1) * 2 + 1];
      float g2f[8];
      dec_fp8x4(d0, g2f);
      dec_fp8x4(d1, g2f + 4);
      s16x8 pb = *reinterpret_cast<const s16x8*>(&Plds[w][c][kk * 32 + q * 8]);
      float sv[8];
#pragma unroll
      for (int j = 0; j < 8; ++j) {
        float x = bf2f(gk[j]) + g2f[j] + bf2f(pb[j]);
        float e = __expf(-x);
        sv[j] = x * __builtin_amdgcn_rcpf(1.f + e);
      }
      i32x4 a2w;
#pragma unroll
      for (int p = 0; p < 4; ++p)
        a2w[p] = (int)cvtpk_bf16(sv[2 * p], sv[2 * p + 1]);
      s16x8 a2 = __builtin_bit_cast(s16x8, a2w);
#pragma unroll
      for (int nt = 0; nt < 8; ++nt) {
        s16x8 b = *reinterpret_cast<const s16x8*>(wp + 36864 + (size_t)(kk * 8 + nt) * 512 + l * 8);
        acc2[nt] = MFMA_BF16(a2, b, acc2[nt], 0, 0, 0);
      }
    }

    // epilogue: wave-private LDS tile + bitmask-driven column-walk
#pragma unroll
    for (int h2 = 0; h2 < 2; ++h2) {
      if (h2) __syncthreads();   // WAR between halves (v8-verified cadence)
#pragma unroll
      for (int nt2 = 0; nt2 < 4; ++nt2) {
        int nt = h2 * 4 + nt2;
        float bias = b2[nt * 16 + c];
#pragma unroll
        for (int r = 0; r < 4; ++r)
          Sred[w][q * 4 + r][nt2 * 16 + c] = acc2[nt][r] + bias;
      }
      float vsum = 0.f;
#pragma unroll
      for (int r = 0; r < 16; ++r) {
        vsum += Sred[w][r][l];
        if ((bm[g] >> r) & 1ull) {
          int rowv = rows_s[g * 64 + we + r];
          if (rowv != SENT)
            unsafeAtomicAdd(&out[(size_t)rowv * 128 + h2 * 64 + l], vsum);
          vsum = 0.f;
        }
      }
    }
  }
}

// ---------- fused edge kernel v7 (r7 verified, fallback for mid-size ws) ----------
__global__ __launch_bounds__(256, 4) void edge_mlp7(
    const short* __restrict__ Gs, const int2* __restrict__ rce,
    const float* __restrict__ bond, const short* __restrict__ wp,
    const float* __restrict__ b1, const float* __restrict__ b2,
    float* __restrict__ out, int E) {
  __shared__ __align__(16) char ubuf[4 * 16 * 136 * 2];
  short (*Plds)[16][136] = reinterpret_cast<short(*)[16][136]>(ubuf);
  float (*Sred)[16][68]  = reinterpret_cast<float(*)[16][68]>(ubuf);
  __shared__ int rows_s[64];
  __shared__ int cols_s[64];
  __shared__ int eidx_s[64];

  const int tid = threadIdx.x;
  const int w = tid >> 6, l = tid & 63;
  const int q = l >> 4, c = l & 15;

  int nwg = gridDim.x;
  int qq = nwg >> 3, rr = nwg & 7;
  int xcd = blockIdx.x & 7, idx = blockIdx.x >> 3;
  int sbid = (xcd < rr ? xcd * (qq + 1) : rr * (qq + 1) + (xcd - rr) * qq) + idx;
  const int eb = sbid * 64;

  if (tid < 64) {
    int gpos = eb + tid;
    if (gpos < E) {
      int2 v = rce[gpos];
      rows_s[tid] = v.x & 0xffff;
      cols_s[tid] = ((unsigned)v.x) >> 16;
      eidx_s[tid] = v.y;
    } else {
      rows_s[tid] = SENT; cols_s[tid] = 0; eidx_s[tid] = 0;
    }
  }
  __syncthreads();

  const int we = w * 16;
  int el = we + c;
  int rv = rows_s[el];
  int rA = (rv == SENT) ? 0 : rv;
  int cA = cols_s[el];
  int eA = eidx_s[el];

  unsigned long long bm = __ballot(
      (l < 16) && (rows_s[we + l] != ((l < 15) ? rows_s[we + l + 1] : -1)));

  s16x8 g1v[4];
  i32x4 g2v[2];
  {
    const short* gb = Gs + (size_t)rA * 192;
#pragma unroll
    for (int kk = 0; kk < 4; ++kk)
      g1v[kk] = *reinterpret_cast<const s16x8*>(gb + kk * 32 + q * 8);
    const char* g2b = (const char*)Gs + (size_t)cA * 384 + 256 + q * 32;
    g2v[0] = *reinterpret_cast<const i32x4*>(g2b);
    g2v[1] = *reinterpret_cast<const i32x4*>(g2b + 16);
  }

  f32x4 accb[8];
#pragma unroll
  for (int nt = 0; nt < 8; ++nt) accb[nt] = (f32x4){0.f, 0.f, 0.f, 0.f};
  {
    s16x8 a = {};
    if (q < 2) {
      const float* src = bond + (size_t)eA * 16 + q * 8;
      a = cvt8(*reinterpret_cast<const f4v*>(src),
               *reinterpret_cast<const f4v*>(src + 4));
    }
#pragma unroll
    for (int nt = 0; nt < 8; ++nt) {
      s16x8 b = *reinterpret_cast<const s16x8*>(wp + (size_t)(64 + nt) * 512 + l * 8);
      accb[nt] = MFMA_BF16(a, b, accb[nt], 0, 0, 0);
    }
  }

#pragma unroll
  for (int nt = 0; nt < 8; ++nt) {
    float bias = b1[nt * 16 + c];
#pragma unroll
    for (int r = 0; r < 4; ++r)
      Plds[w][q * 4 + r][nt * 16 + c] = f2bf(accb[nt][r] + bias);
  }

  f32x4 acc2[8];
#pragma unroll
  for (int nt = 0; nt < 8; ++nt) acc2[nt] = (f32x4){0.f, 0.f, 0.f, 0.f};

#pragma unroll
  for (int kk = 0; kk < 4; ++kk) {
    s16x8 gk = g1v[kk];
    unsigned d0 = (unsigned)g2v[kk >> 1][(kk & 1) * 2 + 0];
    unsigned d1 = (unsigned)g2v[kk >> 1][(kk & 1) * 2 + 1];
    float g2f[8];
    dec_fp8x4(d0, g2f);
    dec_fp8x4(d1, g2f + 4);
    s16x8 pb = *reinterpret_cast<const s16x8*>(&Plds[w][c][kk * 32 + q * 8]);
    s16x8 a2;
#pragma unroll
    for (int j = 0; j < 8; ++j) {
      float x = bf2f(gk[j]) + g2f[j] + bf2f(pb[j]);
      float e = __expf(-x);
      float s = x * __builtin_amdgcn_rcpf(1.f + e);
      a2[j] = f2bf(s);
    }
#pragma unroll
    for (int nt = 0; nt < 8; ++nt) {
      s16x8 b = *reinterpret_cast<const s16x8*>(wp + 36864 + (size_t)(kk * 8 + nt) * 512 + l * 8);
      acc2[nt] = MFMA_BF16(a2, b, acc2[nt], 0, 0, 0);
    }
  }

#pragma unroll
  for (int h2 = 0; h2 < 2; ++h2) {
    if (h2) __syncthreads();
#pragma unroll
    for (int nt2 = 0; nt2 < 4; ++nt2) {
      int nt = h2 * 4 + nt2;
      float bias = b2[nt * 16 + c];
#pragma unroll
      for (int r = 0; r < 4; ++r)
        Sred[w][q * 4 + r][nt2 * 16 + c] = acc2[nt][r] + bias;
    }
    float vsum = 0.f;
#pragma unroll
    for (int r = 0; r < 16; ++r) {
      vsum += Sred[w][r][l];
      if ((bm >> r) & 1ull) {
        int rowv = rows_s[we + r];
        if (rowv != SENT)
          unsafeAtomicAdd(&out[(size_t)rowv * 128 + h2 * 64 + l], vsum);
        vsum = 0.f;
      }
    }
  }
}

// ---------- ultimate fallback (round-1 verified, wp-only) ----------
__global__ __launch_bounds__(256, 2) void edge_mlp(
    const float* __restrict__ h, const int* __restrict__ ei,
    const float* __restrict__ bond, const short* __restrict__ wp,
    const float* __restrict__ b1, const float* __restrict__ b2,
    float* __restrict__ out, int E) {
  __shared__ __align__(16) short Plds[4][64][136];
  __shared__ int rows_s[256];
  __shared__ int cols_s[256];
  const int tid = threadIdx.x;
  const int w = tid >> 6, l = tid & 63;
  const int q = l >> 4, c = l & 15;
  const int eb = blockIdx.x * 256;
  {
    int e = eb + tid; if (e >= E) e = E - 1;
    rows_s[tid] = ei[e];
    cols_s[tid] = ei[(size_t)E + e];
  }
  __syncthreads();
  const int we = w * 64;
  int rN[4], cN[4], eI[4];
#pragma unroll
  for (int mi = 0; mi < 4; ++mi) {
    int el = we + mi * 16 + c;
    rN[mi] = rows_s[el]; cN[mi] = cols_s[el];
    int eg = eb + el; if (eg >= E) eg = E - 1;
    eI[mi] = eg;
  }
  f32x4 acc[4][8];
#pragma unroll
  for (int mi = 0; mi < 4; ++mi)
#pragma unroll
    for (int nt = 0; nt < 8; ++nt) acc[mi][nt] = (f32x4){0.f, 0.f, 0.f, 0.f};
#pragma unroll
  for (int part = 0; part < 2; ++part) {
#pragma unroll
    for (int kk = 0; kk < 4; ++kk) {
      s16x8 a[4];
#pragma unroll
      for (int mi = 0; mi < 4; ++mi) {
        int node = part ? cN[mi] : rN[mi];
        const float* src = h + (size_t)node * 128 + kk * 32 + q * 8;
        a[mi] = cvt8(*reinterpret_cast<const f4v*>(src),
                     *reinterpret_cast<const f4v*>(src + 4));
      }
      const int kkg = part * 4 + kk;
#pragma unroll
      for (int nt = 0; nt < 8; ++nt) {
        s16x8 b = *reinterpret_cast<const s16x8*>(wp + (size_t)(kkg * 8 + nt) * 512 + l * 8);
#pragma unroll
        for (int mi = 0; mi < 4; ++mi)
          acc[mi][nt] = MFMA_BF16(a[mi], b, acc[mi][nt], 0, 0, 0);
      }
    }
  }
  {
    s16x8 a[4];
#pragma unroll
    for (int mi = 0; mi < 4; ++mi) {
      s16x8 az = {};
      if (q < 2) {
        const float* src = bond + (size_t)eI[mi] * 16 + q * 8;
        az = cvt8(*reinterpret_cast<const f4v*>(src),
                  *reinterpret_cast<const f4v*>(src + 4));
      }
      a[mi] = az;
    }
#pragma unroll
    for (int nt = 0; nt < 8; ++nt) {
      s16x8 b = *reinterpret_cast<const s16x8*>(wp + (size_t)(64 + nt) * 512 + l * 8);
#pragma unroll
      for (int mi = 0; mi < 4; ++mi)
        acc[mi][nt] = MFMA_BF16(a[mi], b, acc[mi][nt], 0, 0, 0);
    }
  }
#pragma unroll
  for (int nt = 0; nt < 8; ++nt) {
    float bias = b1[nt * 16 + c];
#pragma unroll
    for (int mi = 0; mi < 4; ++mi)
#pragma unroll
      for (int r = 0; r < 4; ++r) {
        float x = acc[mi][nt][r] + bias;
        float s = x / (1.f + __expf(-x));
        Plds[w][mi * 16 + q * 4 + r][nt * 16 + c] = f2bf(s);
      }
  }
  f32x4 acc2[4][8];
#pragma unroll
  for (int mi = 0; mi < 4; ++mi)
#pragma unroll
    for (int nt = 0; nt < 8; ++nt) acc2[mi][nt] = (f32x4){0.f, 0.f, 0.f, 0.f};
#pragma unroll
  for (int kk = 0; kk < 4; ++kk) {
    s16x8 a2[4];
#pragma unroll
    for (int mi = 0; mi < 4; ++mi)
      a2[mi] = *reinterpret_cast<const s16x8*>(&Plds[w][mi * 16 + c][kk * 32 + q * 8]);
#pragma unroll
    for (int nt = 0; nt < 8; ++nt) {
      s16x8 b = *reinterpret_cast<const s16x8*>(wp + 36864 + (size_t)(kk * 8 + nt) * 512 + l * 8);
#pragma unroll
      for (int mi = 0; mi < 4; ++mi)
        acc2[mi][nt] = MFMA_BF16(a2[mi], b, acc2[mi][nt], 0, 0, 0);
    }
  }
#pragma unroll
  for (int nt = 0; nt < 8; ++nt) {
    float bias = b2[nt * 16 + c];
#pragma unroll
    for (int mi = 0; mi < 4; ++mi)
#pragma unroll
      for (int r = 0; r < 4; ++r) {
        int el = we + mi * 16 + q * 4 + r;
        if ((eb + el) < E) {
          int node = rows_s[el];
          unsafeAtomicAdd(&out[(size_t)node * 128 + nt * 16 + c],
                          acc2[mi][nt][r] + bias);
        }
      }
  }
}

extern "C" void kernel_launch(void* const* d_in, const int* in_sizes, int n_in,
                              void* d_out, int out_size, void* d_ws, size_t ws_size,
                              hipStream_t stream) {
  const float* h    = (const float*)d_in[0];
  const int*   ei   = (const int*)d_in[1];
  const float* bond = (const float*)d_in[2];
  const float* W1   = (const float*)d_in[3];
  const float* b1   = (const float*)d_in[4];
  const float* W2   = (const float*)d_in[5];
  const float* b2   = (const float*)d_in[6];
  float* out = (float*)d_out;
  char* ws = (char*)d_ws;

  const int E  = in_sizes[1] / 2;
  const int NN = in_sizes[0] / 128;

  // ws layout (bytes, 16-aligned)
  short* wp = (short*)ws;                                   // 131072
  size_t off_G    = 131072;
  size_t off_cnt  = off_G + (size_t)NN * 384;
  size_t off_par  = off_cnt + (((size_t)NN * 4 + 15) & ~15ull);
  size_t off_idx  = off_par + 4096;                         // rc (v9: E*4) or rce (v7: E*8)
  size_t off_bs   = off_idx + (((size_t)E * 4 + 15) & ~15ull);
  size_t need9    = off_bs + (size_t)E * 32;                // + sorted bf16 bond
  size_t need7    = off_idx + (size_t)E * 8;

  hipMemsetAsync(d_out, 0, (size_t)NN * 128 * sizeof(float), stream);
  prep_weights<<<26, 256, 0, stream>>>(W1, W2, wp);

  if (ws_size >= need9 && NN <= 65535) {
    short* Gs     = (short*)(ws + off_G);
    int*   cnt    = (int*)(ws + off_cnt);
    int*   par    = (int*)(ws + off_par);
    int*   rc     = (int*)(ws + off_idx);
    short* bond_s = (short*)(ws + off_bs);
    const int NB_G = (NN + 63) / 64;
    const int P    = (NN + 1023) / 1024;

    hipMemsetAsync(cnt, 0, (size_t)NN * 4, stream);
    k_gh<<<NB_G + NB_H, 256, 0, stream>>>(h, wp, Gs, ei, cnt, NN, NB_G, E);
    k_s1<<<P, 1024, 0, stream>>>(cnt, par, NN);
    k_s2<<<1, 1024, 0, stream>>>(par, P);
    k_s3<<<P, 1024, 0, stream>>>(cnt, par, NN);
    k_scatter8<<<2048, 256, 0, stream>>>(ei, cnt, rc, bond_s, bond, E);
    edge_mlp9<<<(E + 127) / 128, 256, 0, stream>>>(Gs, rc, bond_s, wp, b1, b2, out, E);
  } else if (ws_size >= need7 && NN <= 65535) {
    short* Gs   = (short*)(ws + off_G);
    int*   cnt  = (int*)(ws + off_cnt);
    int*   par  = (int*)(ws + off_par);
    int2*  rce  = (int2*)(ws + off_idx);
    const int NB_G = (NN + 63) / 64;
    const int P    = (NN + 1023) / 1024;

    hipMemsetAsync(cnt, 0, (size_t)NN * 4, stream);
    k_gh<<<NB_G + NB_H, 256, 0, stream>>>(h, wp, Gs, ei, cnt, NN, NB_G, E);
    k_s1<<<P, 1024, 0, stream>>>(cnt, par, NN);
    k_s2<<<1, 1024, 0, stream>>>(par, P);
    k_s3<<<P, 1024, 0, stream>>>(cnt, par, NN);
    k_scatter<<<2048, 256, 0, stream>>>(ei, cnt, rce, E);
    edge_mlp7<<<(E + 63) / 64, 256, 0, stream>>>(Gs, rce, bond, wp, b1, b2, out, E);
  } else {
    edge_mlp<<<(E + 255) / 256, 256, 0, stream>>>(h, ei, bond, wp, b1, b2, out, E);
  }
}

// Round 10
// 438.297 us; speedup vs baseline: 1.0601x; 1.0601x over previous
//
#include <hip/hip_runtime.h>

typedef __attribute__((ext_vector_type(4))) float  f32x4;
typedef __attribute__((ext_vector_type(2))) float  f32x2;
typedef __attribute__((ext_vector_type(8))) short  s16x8;
typedef __attribute__((ext_vector_type(4))) float  f4v;
typedef __attribute__((ext_vector_type(4))) int    i32x4;

#define MFMA_BF16 __builtin_amdgcn_mfma_f32_16x16x32_bf16
#define SENT 0x7fffffff

#if defined(__has_builtin)
#if __has_builtin(__builtin_amdgcn_cvt_pk_fp8_f32) && __has_builtin(__builtin_amdgcn_cvt_pk_f32_fp8)
#define HW8 1
#endif
#endif

// ---------- helpers ----------
__device__ __forceinline__ short f2bf(float f) {
  unsigned u = __builtin_bit_cast(unsigned, f);
  u += 0x7fffu + ((u >> 16) & 1u);
  return (short)(u >> 16);
}
__device__ __forceinline__ float bf2f(short s) {
  unsigned u = ((unsigned)(unsigned short)s) << 16;
  return __builtin_bit_cast(float, u);
}
__device__ __forceinline__ s16x8 cvt8(f4v f0, f4v f1) {
  s16x8 r;
  r[0] = f2bf(f0[0]); r[1] = f2bf(f0[1]); r[2] = f2bf(f0[2]); r[3] = f2bf(f0[3]);
  r[4] = f2bf(f1[0]); r[5] = f2bf(f1[1]); r[6] = f2bf(f1[2]); r[7] = f2bf(f1[3]);
  return r;
}
// HW packed bf16 convert (gfx950)
__device__ __forceinline__ unsigned cvtpk_bf16(float a, float b) {
  unsigned r;
  asm("v_cvt_pk_bf16_f32 %0, %1, %2" : "=v"(r) : "v"(a), "v"(b));
  return r;
}
// manual fp8 e4m3fn (fallback when no HW builtin)
__device__ __forceinline__ unsigned f2fp8(float x) {
  unsigned u = __builtin_bit_cast(unsigned, x);
  unsigned s = (u >> 24) & 0x80u;
  unsigned au = u & 0x7fffffffu;
  if (au < 0x3C800000u) return s;
  unsigned biased = au - 0x3C000000u;
  unsigned val = biased >> 20;
  unsigned rem = biased & 0xFFFFFu;
  val += (rem > 0x80000u) || (rem == 0x80000u && (val & 1u));
  if (val > 0x7Eu) val = 0x7Eu;
  return s | val;
}
__device__ __forceinline__ float fp8tof(unsigned b) {
  unsigned em = b & 0x7fu;
  unsigned f = ((em + 960u) << 20) | ((b & 0x80u) << 24);
  return (em < 8u) ? 0.f : __builtin_bit_cast(float, f);
}
__device__ __forceinline__ unsigned char enc_fp8(float x) {
#ifdef HW8
  return (unsigned char)(__builtin_amdgcn_cvt_pk_fp8_f32(x, x, 0u, false) & 0xffu);
#else
  return (unsigned char)f2fp8(x);
#endif
}
__device__ __forceinline__ void dec_fp8x4(unsigned d, float* f) {
#ifdef HW8
  f32x2 lo = __builtin_amdgcn_cvt_pk_f32_fp8(d, false);
  f32x2 hi = __builtin_amdgcn_cvt_pk_f32_fp8(d, true);
  f[0] = lo[0]; f[1] = lo[1]; f[2] = hi[0]; f[3] = hi[1];
#else
#pragma unroll
  for (int j = 0; j < 4; ++j) f[j] = fp8tof((d >> (8 * j)) & 0xffu);
#endif
}

// ---------- weight prep (r4 verified) ----------
__global__ __launch_bounds__(256) void prep_weights(
    const float* __restrict__ W1, const float* __restrict__ W2,
    short* __restrict__ wp) {
  int t = blockIdx.x * 256 + threadIdx.x;
  int chunk = t >> 6, l = t & 63;
  if (chunk >= 104) return;
  int q = l >> 4, c = l & 15;
  s16x8 v;
  if (chunk < 72) {
    int kk = chunk >> 3, nt = chunk & 7;
    int k0 = kk * 32 + q * 8, n = nt * 16 + c;
#pragma unroll
    for (int j = 0; j < 8; ++j) {
      int k = k0 + j;
      v[j] = (k < 272) ? f2bf(W1[k * 128 + n]) : (short)0;
    }
    *reinterpret_cast<s16x8*>(wp + (size_t)chunk * 512 + l * 8) = v;
  } else {
    int c2 = chunk - 72;
    int kk = c2 >> 3, nt = c2 & 7;
    int k0 = kk * 32 + q * 8, n = nt * 16 + c;
#pragma unroll
    for (int j = 0; j < 8; ++j) v[j] = f2bf(W2[(k0 + j) * 128 + n]);
    *reinterpret_cast<s16x8*>(wp + 36864 + (size_t)c2 * 512 + l * 8) = v;
  }
}

// ---------- fused dense G + edge histogram (r4 verified) ----------
// G layout per node: 384 B = [128 bf16 G1 (row half)] [128 B fp8 G2 (col half, permuted)]
#define NB_H 512
__global__ __launch_bounds__(256) void k_gh(
    const float* __restrict__ h, const short* __restrict__ wp,
    short* __restrict__ Gs, const int* __restrict__ ei,
    int* __restrict__ cnt, int NN, int NB_G, int E) {
  if ((int)blockIdx.x >= NB_G) {
    int i = ((int)blockIdx.x - NB_G) * 256 + threadIdx.x;
    for (; i < E; i += NB_H * 256) atomicAdd(&cnt[ei[i]], 1);
    return;
  }
  const int tid = threadIdx.x;
  const int w = tid >> 6, l = tid & 63;
  const int q = l >> 4, c = l & 15;
  const int nb = blockIdx.x * 64 + w * 16;

  f32x4 acc[16];
#pragma unroll
  for (int nt = 0; nt < 16; ++nt) acc[nt] = (f32x4){0.f, 0.f, 0.f, 0.f};

#pragma unroll
  for (int kk = 0; kk < 4; ++kk) {
    int node = nb + c; if (node >= NN) node = NN - 1;
    const float* src = h + (size_t)node * 128 + kk * 32 + q * 8;
    s16x8 a = cvt8(*reinterpret_cast<const f4v*>(src),
                   *reinterpret_cast<const f4v*>(src + 4));
#pragma unroll
    for (int nt2 = 0; nt2 < 16; ++nt2) {
      int kkg = kk + ((nt2 >= 8) ? 4 : 0);
      int chunk = kkg * 8 + (nt2 & 7);
      s16x8 b = *reinterpret_cast<const s16x8*>(wp + (size_t)chunk * 512 + l * 8);
      acc[nt2] = MFMA_BF16(a, b, acc[nt2], 0, 0, 0);
    }
  }
  unsigned char* Gb = (unsigned char*)Gs;
#pragma unroll
  for (int nt2 = 0; nt2 < 16; ++nt2)
#pragma unroll
    for (int r = 0; r < 4; ++r) {
      int node = nb + q * 4 + r;
      if (node < NN) {
        if (nt2 < 8) {
          Gs[(size_t)node * 192 + nt2 * 16 + c] = f2bf(acc[nt2][r]);
        } else {
          int n7 = nt2 - 8;
          int addr = ((n7 & 1) * 2 + (c >> 3)) * 32 + (n7 >> 1) * 8 + (c & 7);
          Gb[(size_t)node * 384 + 256 + addr] = enc_fp8(acc[nt2][r]);
        }
      }
    }
}

// ---------- 3-phase exclusive scan (r4 verified) ----------
__global__ __launch_bounds__(1024) void k_s1(const int* __restrict__ cnt,
                                             int* __restrict__ partial, int NN) {
  __shared__ int red[16];
  int t = threadIdx.x, idx = blockIdx.x * 1024 + t;
  int v = (idx < NN) ? cnt[idx] : 0;
#pragma unroll
  for (int d = 1; d < 64; d <<= 1) v += __shfl_xor(v, d);
  if ((t & 63) == 0) red[t >> 6] = v;
  __syncthreads();
  if (t == 0) {
    int s = 0;
#pragma unroll
    for (int i = 0; i < 16; ++i) s += red[i];
    partial[blockIdx.x] = s;
  }
}
__global__ __launch_bounds__(1024) void k_s2(int* __restrict__ partial, int P) {
  __shared__ int ps[1024];
  int t = threadIdx.x;
  int v = (t < P) ? partial[t] : 0;
  ps[t] = v; __syncthreads();
  for (int d = 1; d < 1024; d <<= 1) {
    int u = (t >= d) ? ps[t - d] : 0;
    __syncthreads(); ps[t] += u; __syncthreads();
  }
  if (t < P) partial[t] = ps[t] - v;
}
__global__ __launch_bounds__(1024) void k_s3(int* __restrict__ cnt,
                                             const int* __restrict__ partial, int NN) {
  __shared__ int ps[1024];
  int t = threadIdx.x, idx = blockIdx.x * 1024 + t;
  int v = (idx < NN) ? cnt[idx] : 0;
  ps[t] = v; __syncthreads();
  for (int d = 1; d < 1024; d <<= 1) {
    int u = (t >= d) ? ps[t - d] : 0;
    __syncthreads(); ps[t] += u; __syncthreads();
  }
  if (idx < NN) cnt[idx] = ps[t] - v + partial[blockIdx.x];
}

// ---------- scatter v8: sorted (row|col) + sorted bf16 bond data (r8 verified) ----------
__global__ void k_scatter8(const int* __restrict__ ei, int* __restrict__ cnt,
                           int* __restrict__ rc, short* __restrict__ bond_s,
                           const float* __restrict__ bond, int E) {
  int i = blockIdx.x * blockDim.x + threadIdx.x;
  int stride = gridDim.x * blockDim.x;
  for (; i < E; i += stride) {
    int r = ei[i], c = ei[(size_t)E + i];
    int pos = atomicAdd(&cnt[r], 1);
    rc[pos] = r | (c << 16);
    const f4v* b4 = reinterpret_cast<const f4v*>(bond + (size_t)i * 16);
    s16x8 lo = cvt8(b4[0], b4[1]);
    s16x8 hi = cvt8(b4[2], b4[3]);
    s16x8* dst = reinterpret_cast<s16x8*>(bond_s + (size_t)pos * 16);
    dst[0] = lo;
    dst[1] = hi;
  }
}

// ---------- scatter v7 (fallback path) ----------
__global__ void k_scatter(const int* __restrict__ ei, int* __restrict__ cnt,
                          int2* __restrict__ rce, int E) {
  int i = blockIdx.x * blockDim.x + threadIdx.x;
  int stride = gridDim.x * blockDim.x;
  for (; i < E; i += stride) {
    int r = ei[i], c = ei[(size_t)E + i];
    int pos = atomicAdd(&cnt[r], 1);
    rce[pos] = make_int2(r | (c << 16), i);
  }
}

// ---------- fused edge kernel v10: barrier-FREE v8 ----------
// 256 thr = 4 waves x 16 sorted edges. Edge metadata via __shfl (no LDS stage,
// no __syncthreads anywhere) -> waves run fully independent. Sentinel row=0xFFFF
// (valid rows <= 65534 under the NN<=65535 launcher guard).
// launch_bounds(256,5): 102-reg cap > ~90-reg live set (no spill), 5 waves/SIMD.
__global__ __launch_bounds__(256, 5) void edge_mlp10(
    const short* __restrict__ Gs, const int* __restrict__ rc,
    const short* __restrict__ bond_s, const short* __restrict__ wp,
    const float* __restrict__ b1, const float* __restrict__ b2,
    float* __restrict__ out, int E) {
  __shared__ __align__(16) char ubuf[4 * 16 * 136 * 2];   // Plds/Sred union, wave-private
  short (*Plds)[16][136] = reinterpret_cast<short(*)[16][136]>(ubuf);
  float (*Sred)[16][68]  = reinterpret_cast<float(*)[16][68]>(ubuf);

  const int tid = threadIdx.x;
  const int w = tid >> 6, l = tid & 63;
  const int q = l >> 4, c = l & 15;

  // XCD-chunked bijective swizzle
  int nwg = gridDim.x;
  int qq = nwg >> 3, rr = nwg & 7;
  int xcd = blockIdx.x & 7, idx = blockIdx.x >> 3;
  int sbid = (xcd < rr ? xcd * (qq + 1) : rr * (qq + 1) + (xcd - rr) * qq) + idx;
  const int eb = sbid * 64;
  const int we = w * 16;

  // per-wave edge metadata: lane l<16 holds packed (row|col<<16) for edge we+l
  int rcv = 0xFFFF;   // sentinel: row=0xFFFF, col=0
  if (l < 16) {
    int gpos = eb + we + l;
    if (gpos < E) rcv = rc[gpos];
  }
  // this lane's A-domain edge (index c within the wave group)
  int v = __shfl(rcv, c);
  int rv = v & 0xffff;
  int rA = (rv == 0xFFFF) ? 0 : rv;
  int cA = ((unsigned)v) >> 16;

  // segment-boundary bitmask (wave-uniform, bits 0..15)
  int vn = __shfl(rcv, (l + 1) & 63);
  unsigned long long bm = __ballot(
      (l < 16) && ((rcv & 0xffff) != ((l < 15) ? (vn & 0xffff) : -1)));

  // ---- hoisted gathers: g1 (bf16, row-local), g2 (fp8, random), bond (sequential) ----
  s16x8 g1v[4];
  i32x4 g2v[2];
  s16x8 az = {};
  {
    const short* gb = Gs + (size_t)rA * 192;
#pragma unroll
    for (int kk = 0; kk < 4; ++kk)
      g1v[kk] = *reinterpret_cast<const s16x8*>(gb + kk * 32 + q * 8);
    const char* g2b = (const char*)Gs + (size_t)cA * 384 + 256 + q * 32;
    g2v[0] = *reinterpret_cast<const i32x4*>(g2b);
    g2v[1] = *reinterpret_cast<const i32x4*>(g2b + 16);
    if (q < 2) {
      int ge = eb + we + c; if (ge >= E) ge = E - 1;
      az = *reinterpret_cast<const s16x8*>(bond_s + (size_t)ge * 16 + q * 8);
    }
  }

  // ---- bond @ W1c (MFMA) ----
  f32x4 accb[8];
#pragma unroll
  for (int nt = 0; nt < 8; ++nt) accb[nt] = (f32x4){0.f, 0.f, 0.f, 0.f};
#pragma unroll
  for (int nt = 0; nt < 8; ++nt) {
    s16x8 b = *reinterpret_cast<const s16x8*>(wp + (size_t)(64 + nt) * 512 + l * 8);
    accb[nt] = MFMA_BF16(az, b, accb[nt], 0, 0, 0);
  }

  // ---- bridge C->A through LDS, fold b1 (wave-private, lgkmcnt-ordered) ----
#pragma unroll
  for (int nt = 0; nt < 8; ++nt) {
    float bias = b1[nt * 16 + c];
#pragma unroll
    for (int r = 0; r < 4; ++r)
      Plds[w][q * 4 + r][nt * 16 + c] = f2bf(accb[nt][r] + bias);
  }

  // ---- GEMM2: A = silu(g1 + g2 + bondterm), packed via v_cvt_pk_bf16_f32 ----
  f32x4 acc2[8];
#pragma unroll
  for (int nt = 0; nt < 8; ++nt) acc2[nt] = (f32x4){0.f, 0.f, 0.f, 0.f};

#pragma unroll
  for (int kk = 0; kk < 4; ++kk) {
    s16x8 gk = g1v[kk];
    unsigned d0 = (unsigned)g2v[kk >> 1][(kk & 1) * 2 + 0];
    unsigned d1 = (unsigned)g2v[kk >> 1][(kk & 1) * 2 + 1];
    float g2f[8];
    dec_fp8x4(d0, g2f);
    dec_fp8x4(d1, g2f + 4);
    s16x8 pb = *reinterpret_cast<const s16x8*>(&Plds[w][c][kk * 32 + q * 8]);
    float sv[8];
#pragma unroll
    for (int j = 0; j < 8; ++j) {
      float x = bf2f(gk[j]) + g2f[j] + bf2f(pb[j]);
      float e = __expf(-x);
      sv[j] = x * __builtin_amdgcn_rcpf(1.f + e);
    }
    i32x4 a2w;
#pragma unroll
    for (int p = 0; p < 4; ++p)
      a2w[p] = (int)cvtpk_bf16(sv[2 * p], sv[2 * p + 1]);
    s16x8 a2 = __builtin_bit_cast(s16x8, a2w);
#pragma unroll
    for (int nt = 0; nt < 8; ++nt) {
      s16x8 b = *reinterpret_cast<const s16x8*>(wp + 36864 + (size_t)(kk * 8 + nt) * 512 + l * 8);
      acc2[nt] = MFMA_BF16(a2, b, acc2[nt], 0, 0, 0);
    }
  }

  // ---- epilogue: wave-private LDS tile + bitmask-driven column-walk (no barriers) ----
#pragma unroll
  for (int h2 = 0; h2 < 2; ++h2) {
#pragma unroll
    for (int nt2 = 0; nt2 < 4; ++nt2) {
      int nt = h2 * 4 + nt2;
      float bias = b2[nt * 16 + c];
#pragma unroll
      for (int r = 0; r < 4; ++r)
        Sred[w][q * 4 + r][nt2 * 16 + c] = acc2[nt][r] + bias;
    }
    // wave-private slice: stores->loads ordered by in-wave lgkmcnt dataflow
    float vsum = 0.f;
#pragma unroll
    for (int r = 0; r < 16; ++r) {
      vsum += Sred[w][r][l];
      if ((bm >> r) & 1ull) {
        int rowv = __shfl(rcv, r) & 0xffff;
        if (rowv != 0xFFFF)
          unsafeAtomicAdd(&out[(size_t)rowv * 128 + h2 * 64 + l], vsum);
        vsum = 0.f;
      }
    }
  }
}

// ---------- fused edge kernel v7 (r7 verified, fallback for mid-size ws) ----------
__global__ __launch_bounds__(256, 4) void edge_mlp7(
    const short* __restrict__ Gs, const int2* __restrict__ rce,
    const float* __restrict__ bond, const short* __restrict__ wp,
    const float* __restrict__ b1, const float* __restrict__ b2,
    float* __restrict__ out, int E) {
  __shared__ __align__(16) char ubuf[4 * 16 * 136 * 2];
  short (*Plds)[16][136] = reinterpret_cast<short(*)[16][136]>(ubuf);
  float (*Sred)[16][68]  = reinterpret_cast<float(*)[16][68]>(ubuf);
  __shared__ int rows_s[64];
  __shared__ int cols_s[64];
  __shared__ int eidx_s[64];

  const int tid = threadIdx.x;
  const int w = tid >> 6, l = tid & 63;
  const int q = l >> 4, c = l & 15;

  int nwg = gridDim.x;
  int qq = nwg >> 3, rr = nwg & 7;
  int xcd = blockIdx.x & 7, idx = blockIdx.x >> 3;
  int sbid = (xcd < rr ? xcd * (qq + 1) : rr * (qq + 1) + (xcd - rr) * qq) + idx;
  const int eb = sbid * 64;

  if (tid < 64) {
    int gpos = eb + tid;
    if (gpos < E) {
      int2 v = rce[gpos];
      rows_s[tid] = v.x & 0xffff;
      cols_s[tid] = ((unsigned)v.x) >> 16;
      eidx_s[tid] = v.y;
    } else {
      rows_s[tid] = SENT; cols_s[tid] = 0; eidx_s[tid] = 0;
    }
  }
  __syncthreads();

  const int we = w * 16;
  int el = we + c;
  int rv = rows_s[el];
  int rA = (rv == SENT) ? 0 : rv;
  int cA = cols_s[el];
  int eA = eidx_s[el];

  unsigned long long bm = __ballot(
      (l < 16) && (rows_s[we + l] != ((l < 15) ? rows_s[we + l + 1] : -1)));

  s16x8 g1v[4];
  i32x4 g2v[2];
  {
    const short* gb = Gs + (size_t)rA * 192;
#pragma unroll
    for (int kk = 0; kk < 4; ++kk)
      g1v[kk] = *reinterpret_cast<const s16x8*>(gb + kk * 32 + q * 8);
    const char* g2b = (const char*)Gs + (size_t)cA * 384 + 256 + q * 32;
    g2v[0] = *reinterpret_cast<const i32x4*>(g2b);
    g2v[1] = *reinterpret_cast<const i32x4*>(g2b + 16);
  }

  f32x4 accb[8];
#pragma unroll
  for (int nt = 0; nt < 8; ++nt) accb[nt] = (f32x4){0.f, 0.f, 0.f, 0.f};
  {
    s16x8 a = {};
    if (q < 2) {
      const float* src = bond + (size_t)eA * 16 + q * 8;
      a = cvt8(*reinterpret_cast<const f4v*>(src),
               *reinterpret_cast<const f4v*>(src + 4));
    }
#pragma unroll
    for (int nt = 0; nt < 8; ++nt) {
      s16x8 b = *reinterpret_cast<const s16x8*>(wp + (size_t)(64 + nt) * 512 + l * 8);
      accb[nt] = MFMA_BF16(a, b, accb[nt], 0, 0, 0);
    }
  }

#pragma unroll
  for (int nt = 0; nt < 8; ++nt) {
    float bias = b1[nt * 16 + c];
#pragma unroll
    for (int r = 0; r < 4; ++r)
      Plds[w][q * 4 + r][nt * 16 + c] = f2bf(accb[nt][r] + bias);
  }

  f32x4 acc2[8];
#pragma unroll
  for (int nt = 0; nt < 8; ++nt) acc2[nt] = (f32x4){0.f, 0.f, 0.f, 0.f};

#pragma unroll
  for (int kk = 0; kk < 4; ++kk) {
    s16x8 gk = g1v[kk];
    unsigned d0 = (unsigned)g2v[kk >> 1][(kk & 1) * 2 + 0];
    unsigned d1 = (unsigned)g2v[kk >> 1][(kk & 1) * 2 + 1];
    float g2f[8];
    dec_fp8x4(d0, g2f);
    dec_fp8x4(d1, g2f + 4);
    s16x8 pb = *reinterpret_cast<const s16x8*>(&Plds[w][c][kk * 32 + q * 8]);
    s16x8 a2;
#pragma unroll
    for (int j = 0; j < 8; ++j) {
      float x = bf2f(gk[j]) + g2f[j] + bf2f(pb[j]);
      float e = __expf(-x);
      float s = x * __builtin_amdgcn_rcpf(1.f + e);
      a2[j] = f2bf(s);
    }
#pragma unroll
    for (int nt = 0; nt < 8; ++nt) {
      s16x8 b = *reinterpret_cast<const s16x8*>(wp + 36864 + (size_t)(kk * 8 + nt) * 512 + l * 8);
      acc2[nt] = MFMA_BF16(a2, b, acc2[nt], 0, 0, 0);
    }
  }

#pragma unroll
  for (int h2 = 0; h2 < 2; ++h2) {
    if (h2) __syncthreads();
#pragma unroll
    for (int nt2 = 0; nt2 < 4; ++nt2) {
      int nt = h2 * 4 + nt2;
      float bias = b2[nt * 16 + c];
#pragma unroll
      for (int r = 0; r < 4; ++r)
        Sred[w][q * 4 + r][nt2 * 16 + c] = acc2[nt][r] + bias;
    }
    float vsum = 0.f;
#pragma unroll
    for (int r = 0; r < 16; ++r) {
      vsum += Sred[w][r][l];
      if ((bm >> r) & 1ull) {
        int rowv = rows_s[we + r];
        if (rowv != SENT)
          unsafeAtomicAdd(&out[(size_t)rowv * 128 + h2 * 64 + l], vsum);
        vsum = 0.f;
      }
    }
  }
}

// ---------- ultimate fallback (round-1 verified, wp-only) ----------
__global__ __launch_bounds__(256, 2) void edge_mlp(
    const float* __restrict__ h, const int* __restrict__ ei,
    const float* __restrict__ bond, const short* __restrict__ wp,
    const float* __restrict__ b1, const float* __restrict__ b2,
    float* __restrict__ out, int E) {
  __shared__ __align__(16) short Plds[4][64][136];
  __shared__ int rows_s[256];
  __shared__ int cols_s[256];
  const int tid = threadIdx.x;
  const int w = tid >> 6, l = tid & 63;
  const int q = l >> 4, c = l & 15;
  const int eb = blockIdx.x * 256;
  {
    int e = eb + tid; if (e >= E) e = E - 1;
    rows_s[tid] = ei[e];
    cols_s[tid] = ei[(size_t)E + e];
  }
  __syncthreads();
  const int we = w * 64;
  int rN[4], cN[4], eI[4];
#pragma unroll
  for (int mi = 0; mi < 4; ++mi) {
    int el = we + mi * 16 + c;
    rN[mi] = rows_s[el]; cN[mi] = cols_s[el];
    int eg = eb + el; if (eg >= E) eg = E - 1;
    eI[mi] = eg;
  }
  f32x4 acc[4][8];
#pragma unroll
  for (int mi = 0; mi < 4; ++mi)
#pragma unroll
    for (int nt = 0; nt < 8; ++nt) acc[mi][nt] = (f32x4){0.f, 0.f, 0.f, 0.f};
#pragma unroll
  for (int part = 0; part < 2; ++part) {
#pragma unroll
    for (int kk = 0; kk < 4; ++kk) {
      s16x8 a[4];
#pragma unroll
      for (int mi = 0; mi < 4; ++mi) {
        int node = part ? cN[mi] : rN[mi];
        const float* src = h + (size_t)node * 128 + kk * 32 + q * 8;
        a[mi] = cvt8(*reinterpret_cast<const f4v*>(src),
                     *reinterpret_cast<const f4v*>(src + 4));
      }
      const int kkg = part * 4 + kk;
#pragma unroll
      for (int nt = 0; nt < 8; ++nt) {
        s16x8 b = *reinterpret_cast<const s16x8*>(wp + (size_t)(kkg * 8 + nt) * 512 + l * 8);
#pragma unroll
        for (int mi = 0; mi < 4; ++mi)
          acc[mi][nt] = MFMA_BF16(a[mi], b, acc[mi][nt], 0, 0, 0);
      }
    }
  }
  {
    s16x8 a[4];
#pragma unroll
    for (int mi = 0; mi < 4; ++mi) {
      s16x8 az = {};
      if (q < 2) {
        const float* src = bond + (size_t)eI[mi] * 16 + q * 8;
        az = cvt8(*reinterpret_cast<const f4v*>(src),
                  *reinterpret_cast<const f4v*>(src + 4));
      }
      a[mi] = az;
    }
#pragma unroll
    for (int nt = 0; nt < 8; ++nt) {
      s16x8 b = *reinterpret_cast<const s16x8*>(wp + (size_t)(64 + nt) * 512 + l * 8);
#pragma unroll
      for (int mi = 0; mi < 4; ++mi)
        acc[mi][nt] = MFMA_BF16(a[mi], b, acc[mi][nt], 0, 0, 0);
    }
  }
#pragma unroll
  for (int nt = 0; nt < 8; ++nt) {
    float bias = b1[nt * 16 + c];
#pragma unroll
    for (int mi = 0; mi < 4; ++mi)
#pragma unroll
      for (int r = 0; r < 4; ++r) {
        float x = acc[mi][nt][r] + bias;
        float s = x / (1.f + __expf(-x));
        Plds[w][mi * 16 + q * 4 + r][nt * 16 + c] = f2bf(s);
      }
  }
  f32x4 acc2[4][8];
#pragma unroll
  for (int mi = 0; mi < 4; ++mi)
#pragma unroll
    for (int nt = 0; nt < 8; ++nt) acc2[mi][nt] = (f32x4){0.f, 0.f, 0.f, 0.f};
#pragma unroll
  for (int kk = 0; kk < 4; ++kk) {
    s16x8 a2[4];
#pragma unroll
    for (int mi = 0; mi < 4; ++mi)
      a2[mi] = *reinterpret_cast<const s16x8*>(&Plds[w][mi * 16 + c][kk * 32 + q * 8]);
#pragma unroll
    for (int nt = 0; nt < 8; ++nt) {
      s16x8 b = *reinterpret_cast<const s16x8*>(wp + 36864 + (size_t)(kk * 8 + nt) * 512 + l * 8);
#pragma unroll
      for (int mi = 0; mi < 4; ++mi)
        acc2[mi][nt] = MFMA_BF16(a2[mi], b, acc2[mi][nt], 0, 0, 0);
    }
  }
#pragma unroll
  for (int nt = 0; nt < 8; ++nt) {
    float bias = b2[nt * 16 + c];
#pragma unroll
    for (int mi = 0; mi < 4; ++mi)
#pragma unroll
      for (int r = 0; r < 4; ++r) {
        int el = we + mi * 16 + q * 4 + r;
        if ((eb + el) < E) {
          int node = rows_s[el];
          unsafeAtomicAdd(&out[(size_t)node * 128 + nt * 16 + c],
                          acc2[mi][nt][r] + bias);
        }
      }
  }
}

extern "C" void kernel_launch(void* const* d_in, const int* in_sizes, int n_in,
                              void* d_out, int out_size, void* d_ws, size_t ws_size,
                              hipStream_t stream) {
  const float* h    = (const float*)d_in[0];
  const int*   ei   = (const int*)d_in[1];
  const float* bond = (const float*)d_in[2];
  const float* W1   = (const float*)d_in[3];
  const float* b1   = (const float*)d_in[4];
  const float* W2   = (const float*)d_in[5];
  const float* b2   = (const float*)d_in[6];
  float* out = (float*)d_out;
  char* ws = (char*)d_ws;

  const int E  = in_sizes[1] / 2;
  const int NN = in_sizes[0] / 128;

  // ws layout (bytes, 16-aligned)
  short* wp = (short*)ws;                                   // 131072
  size_t off_G    = 131072;
  size_t off_cnt  = off_G + (size_t)NN * 384;
  size_t off_par  = off_cnt + (((size_t)NN * 4 + 15) & ~15ull);
  size_t off_idx  = off_par + 4096;                         // rc (v10: E*4) or rce (v7: E*8)
  size_t off_bs   = off_idx + (((size_t)E * 4 + 15) & ~15ull);
  size_t need10   = off_bs + (size_t)E * 32;                // + sorted bf16 bond
  size_t need7    = off_idx + (size_t)E * 8;

  hipMemsetAsync(d_out, 0, (size_t)NN * 128 * sizeof(float), stream);
  prep_weights<<<26, 256, 0, stream>>>(W1, W2, wp);

  if (ws_size >= need10 && NN <= 65535) {
    short* Gs     = (short*)(ws + off_G);
    int*   cnt    = (int*)(ws + off_cnt);
    int*   par    = (int*)(ws + off_par);
    int*   rc     = (int*)(ws + off_idx);
    short* bond_s = (short*)(ws + off_bs);
    const int NB_G = (NN + 63) / 64;
    const int P    = (NN + 1023) / 1024;

    hipMemsetAsync(cnt, 0, (size_t)NN * 4, stream);
    k_gh<<<NB_G + NB_H, 256, 0, stream>>>(h, wp, Gs, ei, cnt, NN, NB_G, E);
    k_s1<<<P, 1024, 0, stream>>>(cnt, par, NN);
    k_s2<<<1, 1024, 0, stream>>>(par, P);
    k_s3<<<P, 1024, 0, stream>>>(cnt, par, NN);
    k_scatter8<<<2048, 256, 0, stream>>>(ei, cnt, rc, bond_s, bond, E);
    edge_mlp10<<<(E + 63) / 64, 256, 0, stream>>>(Gs, rc, bond_s, wp, b1, b2, out, E);
  } else if (ws_size >= need7 && NN <= 65535) {
    short* Gs   = (short*)(ws + off_G);
    int*   cnt  = (int*)(ws + off_cnt);
    int*   par  = (int*)(ws + off_par);
    int2*  rce  = (int2*)(ws + off_idx);
    const int NB_G = (NN + 63) / 64;
    const int P    = (NN + 1023) / 1024;

    hipMemsetAsync(cnt, 0, (size_t)NN * 4, stream);
    k_gh<<<NB_G + NB_H, 256, 0, stream>>>(h, wp, Gs, ei, cnt, NN, NB_G, E);
    k_s1<<<P, 1024, 0, stream>>>(cnt, par, NN);
    k_s2<<<1, 1024, 0, stream>>>(par, P);
    k_s3<<<P, 1024, 0, stream>>>(cnt, par, NN);
    k_scatter<<<2048, 256, 0, stream>>>(ei, cnt, rce, E);
    edge_mlp7<<<(E + 63) / 64, 256, 0, stream>>>(Gs, rce, bond, wp, b1, b2, out, E);
  } else {
    edge_mlp<<<(E + 255) / 256, 256, 0, stream>>>(h, ei, bond, wp, b1, b2, out, E);
  }
}

// Round 11
// 438.182 us; speedup vs baseline: 1.0604x; 1.0003x over previous
//
#include <hip/hip_runtime.h>

typedef __attribute__((ext_vector_type(4))) float  f32x4;
typedef __attribute__((ext_vector_type(2))) float  f32x2;
typedef __attribute__((ext_vector_type(8))) short  s16x8;
typedef __attribute__((ext_vector_type(4))) float  f4v;
typedef __attribute__((ext_vector_type(4))) int    i32x4;

#define MFMA_BF16 __builtin_amdgcn_mfma_f32_16x16x32_bf16
#define SENT 0x7fffffff

#if defined(__has_builtin)
#if __has_builtin(__builtin_amdgcn_cvt_pk_fp8_f32) && __has_builtin(__builtin_amdgcn_cvt_pk_f32_fp8)
#define HW8 1
#endif
#endif

// ---------- helpers ----------
__device__ __forceinline__ short f2bf(float f) {
  unsigned u = __builtin_bit_cast(unsigned, f);
  u += 0x7fffu + ((u >> 16) & 1u);
  return (short)(u >> 16);
}
__device__ __forceinline__ float bf2f(short s) {
  unsigned u = ((unsigned)(unsigned short)s) << 16;
  return __builtin_bit_cast(float, u);
}
__device__ __forceinline__ s16x8 cvt8(f4v f0, f4v f1) {
  s16x8 r;
  r[0] = f2bf(f0[0]); r[1] = f2bf(f0[1]); r[2] = f2bf(f0[2]); r[3] = f2bf(f0[3]);
  r[4] = f2bf(f1[0]); r[5] = f2bf(f1[1]); r[6] = f2bf(f1[2]); r[7] = f2bf(f1[3]);
  return r;
}
// HW packed bf16 convert (gfx950)
__device__ __forceinline__ unsigned cvtpk_bf16(float a, float b) {
  unsigned r;
  asm("v_cvt_pk_bf16_f32 %0, %1, %2" : "=v"(r) : "v"(a), "v"(b));
  return r;
}
// manual fp8 e4m3fn (fallback when no HW builtin)
__device__ __forceinline__ unsigned f2fp8(float x) {
  unsigned u = __builtin_bit_cast(unsigned, x);
  unsigned s = (u >> 24) & 0x80u;
  unsigned au = u & 0x7fffffffu;
  if (au < 0x3C800000u) return s;
  unsigned biased = au - 0x3C000000u;
  unsigned val = biased >> 20;
  unsigned rem = biased & 0xFFFFFu;
  val += (rem > 0x80000u) || (rem == 0x80000u && (val & 1u));
  if (val > 0x7Eu) val = 0x7Eu;
  return s | val;
}
__device__ __forceinline__ float fp8tof(unsigned b) {
  unsigned em = b & 0x7fu;
  unsigned f = ((em + 960u) << 20) | ((b & 0x80u) << 24);
  return (em < 8u) ? 0.f : __builtin_bit_cast(float, f);
}
__device__ __forceinline__ unsigned char enc_fp8(float x) {
#ifdef HW8
  return (unsigned char)(__builtin_amdgcn_cvt_pk_fp8_f32(x, x, 0u, false) & 0xffu);
#else
  return (unsigned char)f2fp8(x);
#endif
}
__device__ __forceinline__ void dec_fp8x4(unsigned d, float* f) {
#ifdef HW8
  f32x2 lo = __builtin_amdgcn_cvt_pk_f32_fp8(d, false);
  f32x2 hi = __builtin_amdgcn_cvt_pk_f32_fp8(d, true);
  f[0] = lo[0]; f[1] = lo[1]; f[2] = hi[0]; f[3] = hi[1];
#else
#pragma unroll
  for (int j = 0; j < 4; ++j) f[j] = fp8tof((d >> (8 * j)) & 0xffu);
#endif
}

// ---------- weight prep (r4 verified) ----------
__global__ __launch_bounds__(256) void prep_weights(
    const float* __restrict__ W1, const float* __restrict__ W2,
    short* __restrict__ wp) {
  int t = blockIdx.x * 256 + threadIdx.x;
  int chunk = t >> 6, l = t & 63;
  if (chunk >= 104) return;
  int q = l >> 4, c = l & 15;
  s16x8 v;
  if (chunk < 72) {
    int kk = chunk >> 3, nt = chunk & 7;
    int k0 = kk * 32 + q * 8, n = nt * 16 + c;
#pragma unroll
    for (int j = 0; j < 8; ++j) {
      int k = k0 + j;
      v[j] = (k < 272) ? f2bf(W1[k * 128 + n]) : (short)0;
    }
    *reinterpret_cast<s16x8*>(wp + (size_t)chunk * 512 + l * 8) = v;
  } else {
    int c2 = chunk - 72;
    int kk = c2 >> 3, nt = c2 & 7;
    int k0 = kk * 32 + q * 8, n = nt * 16 + c;
#pragma unroll
    for (int j = 0; j < 8; ++j) v[j] = f2bf(W2[(k0 + j) * 128 + n]);
    *reinterpret_cast<s16x8*>(wp + 36864 + (size_t)c2 * 512 + l * 8) = v;
  }
}

// ---------- fused dense G + edge histogram (r4 verified) ----------
// G layout per node: 384 B = [128 bf16 G1 (row half)] [128 B fp8 G2 (col half, permuted)]
#define NB_H 512
__global__ __launch_bounds__(256) void k_gh(
    const float* __restrict__ h, const short* __restrict__ wp,
    short* __restrict__ Gs, const int* __restrict__ ei,
    int* __restrict__ cnt, int NN, int NB_G, int E) {
  if ((int)blockIdx.x >= NB_G) {
    int i = ((int)blockIdx.x - NB_G) * 256 + threadIdx.x;
    for (; i < E; i += NB_H * 256) atomicAdd(&cnt[ei[i]], 1);
    return;
  }
  const int tid = threadIdx.x;
  const int w = tid >> 6, l = tid & 63;
  const int q = l >> 4, c = l & 15;
  const int nb = blockIdx.x * 64 + w * 16;

  f32x4 acc[16];
#pragma unroll
  for (int nt = 0; nt < 16; ++nt) acc[nt] = (f32x4){0.f, 0.f, 0.f, 0.f};

#pragma unroll
  for (int kk = 0; kk < 4; ++kk) {
    int node = nb + c; if (node >= NN) node = NN - 1;
    const float* src = h + (size_t)node * 128 + kk * 32 + q * 8;
    s16x8 a = cvt8(*reinterpret_cast<const f4v*>(src),
                   *reinterpret_cast<const f4v*>(src + 4));
#pragma unroll
    for (int nt2 = 0; nt2 < 16; ++nt2) {
      int kkg = kk + ((nt2 >= 8) ? 4 : 0);
      int chunk = kkg * 8 + (nt2 & 7);
      s16x8 b = *reinterpret_cast<const s16x8*>(wp + (size_t)chunk * 512 + l * 8);
      acc[nt2] = MFMA_BF16(a, b, acc[nt2], 0, 0, 0);
    }
  }
  unsigned char* Gb = (unsigned char*)Gs;
#pragma unroll
  for (int nt2 = 0; nt2 < 16; ++nt2)
#pragma unroll
    for (int r = 0; r < 4; ++r) {
      int node = nb + q * 4 + r;
      if (node < NN) {
        if (nt2 < 8) {
          Gs[(size_t)node * 192 + nt2 * 16 + c] = f2bf(acc[nt2][r]);
        } else {
          int n7 = nt2 - 8;
          int addr = ((n7 & 1) * 2 + (c >> 3)) * 32 + (n7 >> 1) * 8 + (c & 7);
          Gb[(size_t)node * 384 + 256 + addr] = enc_fp8(acc[nt2][r]);
        }
      }
    }
}

// ---------- 3-phase exclusive scan (r4 verified) ----------
__global__ __launch_bounds__(1024) void k_s1(const int* __restrict__ cnt,
                                             int* __restrict__ partial, int NN) {
  __shared__ int red[16];
  int t = threadIdx.x, idx = blockIdx.x * 1024 + t;
  int v = (idx < NN) ? cnt[idx] : 0;
#pragma unroll
  for (int d = 1; d < 64; d <<= 1) v += __shfl_xor(v, d);
  if ((t & 63) == 0) red[t >> 6] = v;
  __syncthreads();
  if (t == 0) {
    int s = 0;
#pragma unroll
    for (int i = 0; i < 16; ++i) s += red[i];
    partial[blockIdx.x] = s;
  }
}
__global__ __launch_bounds__(1024) void k_s2(int* __restrict__ partial, int P) {
  __shared__ int ps[1024];
  int t = threadIdx.x;
  int v = (t < P) ? partial[t] : 0;
  ps[t] = v; __syncthreads();
  for (int d = 1; d < 1024; d <<= 1) {
    int u = (t >= d) ? ps[t - d] : 0;
    __syncthreads(); ps[t] += u; __syncthreads();
  }
  if (t < P) partial[t] = ps[t] - v;
}
__global__ __launch_bounds__(1024) void k_s3(int* __restrict__ cnt,
                                             const int* __restrict__ partial, int NN) {
  __shared__ int ps[1024];
  int t = threadIdx.x, idx = blockIdx.x * 1024 + t;
  int v = (idx < NN) ? cnt[idx] : 0;
  ps[t] = v; __syncthreads();
  for (int d = 1; d < 1024; d <<= 1) {
    int u = (t >= d) ? ps[t - d] : 0;
    __syncthreads(); ps[t] += u; __syncthreads();
  }
  if (idx < NN) cnt[idx] = ps[t] - v + partial[blockIdx.x];
}

// ---------- scatter v8: sorted (row|col) + sorted bf16 bond data (r8 verified) ----------
__global__ void k_scatter8(const int* __restrict__ ei, int* __restrict__ cnt,
                           int* __restrict__ rc, short* __restrict__ bond_s,
                           const float* __restrict__ bond, int E) {
  int i = blockIdx.x * blockDim.x + threadIdx.x;
  int stride = gridDim.x * blockDim.x;
  for (; i < E; i += stride) {
    int r = ei[i], c = ei[(size_t)E + i];
    int pos = atomicAdd(&cnt[r], 1);
    rc[pos] = r | (c << 16);
    const f4v* b4 = reinterpret_cast<const f4v*>(bond + (size_t)i * 16);
    s16x8 lo = cvt8(b4[0], b4[1]);
    s16x8 hi = cvt8(b4[2], b4[3]);
    s16x8* dst = reinterpret_cast<s16x8*>(bond_s + (size_t)pos * 16);
    dst[0] = lo;
    dst[1] = hi;
  }
}

// ---------- scatter v7 (fallback path) ----------
__global__ void k_scatter(const int* __restrict__ ei, int* __restrict__ cnt,
                          int2* __restrict__ rce, int E) {
  int i = blockIdx.x * blockDim.x + threadIdx.x;
  int stride = gridDim.x * blockDim.x;
  for (; i < E; i += stride) {
    int r = ei[i], c = ei[(size_t)E + i];
    int pos = atomicAdd(&cnt[r], 1);
    rce[pos] = make_int2(r | (c << 16), i);
  }
}

// ---------- fused edge kernel v11: v10 + merged accumulator + cvt_pk bridge ----------
// 256 thr = 4 waves x 16 sorted edges, barrier-free (v10 verified structure).
// ONE acc[8] serves both the bond-MFMA phase and GEMM2 (disjoint lifetimes)
// -> ~32 fewer AGPRs -> target 6 waves/SIMD. Bridge uses v_cvt_pk_bf16_f32.
__global__ __launch_bounds__(256, 5) void edge_mlp11(
    const short* __restrict__ Gs, const int* __restrict__ rc,
    const short* __restrict__ bond_s, const short* __restrict__ wp,
    const float* __restrict__ b1, const float* __restrict__ b2,
    float* __restrict__ out, int E) {
  __shared__ __align__(16) char ubuf[4 * 16 * 136 * 2];   // Plds/Sred union, wave-private
  short (*Plds)[16][136] = reinterpret_cast<short(*)[16][136]>(ubuf);
  float (*Sred)[16][68]  = reinterpret_cast<float(*)[16][68]>(ubuf);

  const int tid = threadIdx.x;
  const int w = tid >> 6, l = tid & 63;
  const int q = l >> 4, c = l & 15;

  // XCD-chunked bijective swizzle
  int nwg = gridDim.x;
  int qq = nwg >> 3, rr = nwg & 7;
  int xcd = blockIdx.x & 7, idx = blockIdx.x >> 3;
  int sbid = (xcd < rr ? xcd * (qq + 1) : rr * (qq + 1) + (xcd - rr) * qq) + idx;
  const int eb = sbid * 64;
  const int we = w * 16;

  // per-wave edge metadata: lane l<16 holds packed (row|col<<16) for edge we+l
  int rcv = 0xFFFF;   // sentinel: row=0xFFFF, col=0
  if (l < 16) {
    int gpos = eb + we + l;
    if (gpos < E) rcv = rc[gpos];
  }
  int v = __shfl(rcv, c);
  int rv = v & 0xffff;
  int rA = (rv == 0xFFFF) ? 0 : rv;
  int cA = ((unsigned)v) >> 16;

  // segment-boundary bitmask (wave-uniform, bits 0..15)
  int vn = __shfl(rcv, (l + 1) & 63);
  unsigned long long bm = __ballot(
      (l < 16) && ((rcv & 0xffff) != ((l < 15) ? (vn & 0xffff) : -1)));

  // ---- hoisted gathers: g1 (bf16, row-local), g2 (fp8, random), bond (sequential) ----
  s16x8 g1v[4];
  i32x4 g2v[2];
  s16x8 az = {};
  {
    const short* gb = Gs + (size_t)rA * 192;
#pragma unroll
    for (int kk = 0; kk < 4; ++kk)
      g1v[kk] = *reinterpret_cast<const s16x8*>(gb + kk * 32 + q * 8);
    const char* g2b = (const char*)Gs + (size_t)cA * 384 + 256 + q * 32;
    g2v[0] = *reinterpret_cast<const i32x4*>(g2b);
    g2v[1] = *reinterpret_cast<const i32x4*>(g2b + 16);
    if (q < 2) {
      int ge = eb + we + c; if (ge >= E) ge = E - 1;
      az = *reinterpret_cast<const s16x8*>(bond_s + (size_t)ge * 16 + q * 8);
    }
  }

  // ---- phase 1: bond @ W1c (MFMA) into shared acc ----
  f32x4 acc[8];
#pragma unroll
  for (int nt = 0; nt < 8; ++nt) acc[nt] = (f32x4){0.f, 0.f, 0.f, 0.f};
#pragma unroll
  for (int nt = 0; nt < 8; ++nt) {
    s16x8 b = *reinterpret_cast<const s16x8*>(wp + (size_t)(64 + nt) * 512 + l * 8);
    acc[nt] = MFMA_BF16(az, b, acc[nt], 0, 0, 0);
  }

  // ---- bridge C->A through LDS, fold b1 (cvt_pk pairs; wave-private, lgkmcnt-ordered) ----
#pragma unroll
  for (int nt = 0; nt < 8; ++nt) {
    float bias = b1[nt * 16 + c];
    unsigned p01 = cvtpk_bf16(acc[nt][0] + bias, acc[nt][1] + bias);
    unsigned p23 = cvtpk_bf16(acc[nt][2] + bias, acc[nt][3] + bias);
    Plds[w][q * 4 + 0][nt * 16 + c] = (short)(p01 & 0xffffu);
    Plds[w][q * 4 + 1][nt * 16 + c] = (short)(p01 >> 16);
    Plds[w][q * 4 + 2][nt * 16 + c] = (short)(p23 & 0xffffu);
    Plds[w][q * 4 + 3][nt * 16 + c] = (short)(p23 >> 16);
  }

  // ---- phase 2: re-zero acc, GEMM2: A = silu(g1 + g2 + bondterm) ----
#pragma unroll
  for (int nt = 0; nt < 8; ++nt) acc[nt] = (f32x4){0.f, 0.f, 0.f, 0.f};

#pragma unroll
  for (int kk = 0; kk < 4; ++kk) {
    s16x8 gk = g1v[kk];
    unsigned d0 = (unsigned)g2v[kk >> 1][(kk & 1) * 2 + 0];
    unsigned d1 = (unsigned)g2v[kk >> 1][(kk & 1) * 2 + 1];
    float g2f[8];
    dec_fp8x4(d0, g2f);
    dec_fp8x4(d1, g2f + 4);
    s16x8 pb = *reinterpret_cast<const s16x8*>(&Plds[w][c][kk * 32 + q * 8]);
    float sv[8];
#pragma unroll
    for (int j = 0; j < 8; ++j) {
      float x = bf2f(gk[j]) + g2f[j] + bf2f(pb[j]);
      float e = __expf(-x);
      sv[j] = x * __builtin_amdgcn_rcpf(1.f + e);
    }
    i32x4 a2w;
#pragma unroll
    for (int p = 0; p < 4; ++p)
      a2w[p] = (int)cvtpk_bf16(sv[2 * p], sv[2 * p + 1]);
    s16x8 a2 = __builtin_bit_cast(s16x8, a2w);
#pragma unroll
    for (int nt = 0; nt < 8; ++nt) {
      s16x8 b = *reinterpret_cast<const s16x8*>(wp + 36864 + (size_t)(kk * 8 + nt) * 512 + l * 8);
      acc[nt] = MFMA_BF16(a2, b, acc[nt], 0, 0, 0);
    }
  }

  // ---- epilogue: wave-private LDS tile + bitmask-driven column-walk (no barriers) ----
#pragma unroll
  for (int h2 = 0; h2 < 2; ++h2) {
#pragma unroll
    for (int nt2 = 0; nt2 < 4; ++nt2) {
      int nt = h2 * 4 + nt2;
      float bias = b2[nt * 16 + c];
#pragma unroll
      for (int r = 0; r < 4; ++r)
        Sred[w][q * 4 + r][nt2 * 16 + c] = acc[nt][r] + bias;
    }
    // wave-private slice: stores->loads ordered by in-wave lgkmcnt dataflow
    float vsum = 0.f;
#pragma unroll
    for (int r = 0; r < 16; ++r) {
      vsum += Sred[w][r][l];
      if ((bm >> r) & 1ull) {
        int rowv = __shfl(rcv, r) & 0xffff;
        if (rowv != 0xFFFF)
          unsafeAtomicAdd(&out[(size_t)rowv * 128 + h2 * 64 + l], vsum);
        vsum = 0.f;
      }
    }
  }
}

// ---------- fused edge kernel v7 (r7 verified, fallback for mid-size ws) ----------
__global__ __launch_bounds__(256, 4) void edge_mlp7(
    const short* __restrict__ Gs, const int2* __restrict__ rce,
    const float* __restrict__ bond, const short* __restrict__ wp,
    const float* __restrict__ b1, const float* __restrict__ b2,
    float* __restrict__ out, int E) {
  __shared__ __align__(16) char ubuf[4 * 16 * 136 * 2];
  short (*Plds)[16][136] = reinterpret_cast<short(*)[16][136]>(ubuf);
  float (*Sred)[16][68]  = reinterpret_cast<float(*)[16][68]>(ubuf);
  __shared__ int rows_s[64];
  __shared__ int cols_s[64];
  __shared__ int eidx_s[64];

  const int tid = threadIdx.x;
  const int w = tid >> 6, l = tid & 63;
  const int q = l >> 4, c = l & 15;

  int nwg = gridDim.x;
  int qq = nwg >> 3, rr = nwg & 7;
  int xcd = blockIdx.x & 7, idx = blockIdx.x >> 3;
  int sbid = (xcd < rr ? xcd * (qq + 1) : rr * (qq + 1) + (xcd - rr) * qq) + idx;
  const int eb = sbid * 64;

  if (tid < 64) {
    int gpos = eb + tid;
    if (gpos < E) {
      int2 v = rce[gpos];
      rows_s[tid] = v.x & 0xffff;
      cols_s[tid] = ((unsigned)v.x) >> 16;
      eidx_s[tid] = v.y;
    } else {
      rows_s[tid] = SENT; cols_s[tid] = 0; eidx_s[tid] = 0;
    }
  }
  __syncthreads();

  const int we = w * 16;
  int el = we + c;
  int rv = rows_s[el];
  int rA = (rv == SENT) ? 0 : rv;
  int cA = cols_s[el];
  int eA = eidx_s[el];

  unsigned long long bm = __ballot(
      (l < 16) && (rows_s[we + l] != ((l < 15) ? rows_s[we + l + 1] : -1)));

  s16x8 g1v[4];
  i32x4 g2v[2];
  {
    const short* gb = Gs + (size_t)rA * 192;
#pragma unroll
    for (int kk = 0; kk < 4; ++kk)
      g1v[kk] = *reinterpret_cast<const s16x8*>(gb + kk * 32 + q * 8);
    const char* g2b = (const char*)Gs + (size_t)cA * 384 + 256 + q * 32;
    g2v[0] = *reinterpret_cast<const i32x4*>(g2b);
    g2v[1] = *reinterpret_cast<const i32x4*>(g2b + 16);
  }

  f32x4 accb[8];
#pragma unroll
  for (int nt = 0; nt < 8; ++nt) accb[nt] = (f32x4){0.f, 0.f, 0.f, 0.f};
  {
    s16x8 a = {};
    if (q < 2) {
      const float* src = bond + (size_t)eA * 16 + q * 8;
      a = cvt8(*reinterpret_cast<const f4v*>(src),
               *reinterpret_cast<const f4v*>(src + 4));
    }
#pragma unroll
    for (int nt = 0; nt < 8; ++nt) {
      s16x8 b = *reinterpret_cast<const s16x8*>(wp + (size_t)(64 + nt) * 512 + l * 8);
      accb[nt] = MFMA_BF16(a, b, accb[nt], 0, 0, 0);
    }
  }

#pragma unroll
  for (int nt = 0; nt < 8; ++nt) {
    float bias = b1[nt * 16 + c];
#pragma unroll
    for (int r = 0; r < 4; ++r)
      Plds[w][q * 4 + r][nt * 16 + c] = f2bf(accb[nt][r] + bias);
  }

  f32x4 acc2[8];
#pragma unroll
  for (int nt = 0; nt < 8; ++nt) acc2[nt] = (f32x4){0.f, 0.f, 0.f, 0.f};

#pragma unroll
  for (int kk = 0; kk < 4; ++kk) {
    s16x8 gk = g1v[kk];
    unsigned d0 = (unsigned)g2v[kk >> 1][(kk & 1) * 2 + 0];
    unsigned d1 = (unsigned)g2v[kk >> 1][(kk & 1) * 2 + 1];
    float g2f[8];
    dec_fp8x4(d0, g2f);
    dec_fp8x4(d1, g2f + 4);
    s16x8 pb = *reinterpret_cast<const s16x8*>(&Plds[w][c][kk * 32 + q * 8]);
    s16x8 a2;
#pragma unroll
    for (int j = 0; j < 8; ++j) {
      float x = bf2f(gk[j]) + g2f[j] + bf2f(pb[j]);
      float e = __expf(-x);
      float s = x * __builtin_amdgcn_rcpf(1.f + e);
      a2[j] = f2bf(s);
    }
#pragma unroll
    for (int nt = 0; nt < 8; ++nt) {
      s16x8 b = *reinterpret_cast<const s16x8*>(wp + 36864 + (size_t)(kk * 8 + nt) * 512 + l * 8);
      acc2[nt] = MFMA_BF16(a2, b, acc2[nt], 0, 0, 0);
    }
  }

#pragma unroll
  for (int h2 = 0; h2 < 2; ++h2) {
    if (h2) __syncthreads();
#pragma unroll
    for (int nt2 = 0; nt2 < 4; ++nt2) {
      int nt = h2 * 4 + nt2;
      float bias = b2[nt * 16 + c];
#pragma unroll
      for (int r = 0; r < 4; ++r)
        Sred[w][q * 4 + r][nt2 * 16 + c] = acc2[nt][r] + bias;
    }
    float vsum = 0.f;
#pragma unroll
    for (int r = 0; r < 16; ++r) {
      vsum += Sred[w][r][l];
      if ((bm >> r) & 1ull) {
        int rowv = rows_s[we + r];
        if (rowv != SENT)
          unsafeAtomicAdd(&out[(size_t)rowv * 128 + h2 * 64 + l], vsum);
        vsum = 0.f;
      }
    }
  }
}

// ---------- ultimate fallback (round-1 verified, wp-only) ----------
__global__ __launch_bounds__(256, 2) void edge_mlp(
    const float* __restrict__ h, const int* __restrict__ ei,
    const float* __restrict__ bond, const short* __restrict__ wp,
    const float* __restrict__ b1, const float* __restrict__ b2,
    float* __restrict__ out, int E) {
  __shared__ __align__(16) short Plds[4][64][136];
  __shared__ int rows_s[256];
  __shared__ int cols_s[256];
  const int tid = threadIdx.x;
  const int w = tid >> 6, l = tid & 63;
  const int q = l >> 4, c = l & 15;
  const int eb = blockIdx.x * 256;
  {
    int e = eb + tid; if (e >= E) e = E - 1;
    rows_s[tid] = ei[e];
    cols_s[tid] = ei[(size_t)E + e];
  }
  __syncthreads();
  const int we = w * 64;
  int rN[4], cN[4], eI[4];
#pragma unroll
  for (int mi = 0; mi < 4; ++mi) {
    int el = we + mi * 16 + c;
    rN[mi] = rows_s[el]; cN[mi] = cols_s[el];
    int eg = eb + el; if (eg >= E) eg = E - 1;
    eI[mi] = eg;
  }
  f32x4 acc[4][8];
#pragma unroll
  for (int mi = 0; mi < 4; ++mi)
#pragma unroll
    for (int nt = 0; nt < 8; ++nt) acc[mi][nt] = (f32x4){0.f, 0.f, 0.f, 0.f};
#pragma unroll
  for (int part = 0; part < 2; ++part) {
#pragma unroll
    for (int kk = 0; kk < 4; ++kk) {
      s16x8 a[4];
#pragma unroll
      for (int mi = 0; mi < 4; ++mi) {
        int node = part ? cN[mi] : rN[mi];
        const float* src = h + (size_t)node * 128 + kk * 32 + q * 8;
        a[mi] = cvt8(*reinterpret_cast<const f4v*>(src),
                     *reinterpret_cast<const f4v*>(src + 4));
      }
      const int kkg = part * 4 + kk;
#pragma unroll
      for (int nt = 0; nt < 8; ++nt) {
        s16x8 b = *reinterpret_cast<const s16x8*>(wp + (size_t)(kkg * 8 + nt) * 512 + l * 8);
#pragma unroll
        for (int mi = 0; mi < 4; ++mi)
          acc[mi][nt] = MFMA_BF16(a[mi], b, acc[mi][nt], 0, 0, 0);
      }
    }
  }
  {
    s16x8 a[4];
#pragma unroll
    for (int mi = 0; mi < 4; ++mi) {
      s16x8 az = {};
      if (q < 2) {
        const float* src = bond + (size_t)eI[mi] * 16 + q * 8;
        az = cvt8(*reinterpret_cast<const f4v*>(src),
                  *reinterpret_cast<const f4v*>(src + 4));
      }
      a[mi] = az;
    }
#pragma unroll
    for (int nt = 0; nt < 8; ++nt) {
      s16x8 b = *reinterpret_cast<const s16x8*>(wp + (size_t)(64 + nt) * 512 + l * 8);
#pragma unroll
      for (int mi = 0; mi < 4; ++mi)
        acc[mi][nt] = MFMA_BF16(a[mi], b, acc[mi][nt], 0, 0, 0);
    }
  }
#pragma unroll
  for (int nt = 0; nt < 8; ++nt) {
    float bias = b1[nt * 16 + c];
#pragma unroll
    for (int mi = 0; mi < 4; ++mi)
#pragma unroll
      for (int r = 0; r < 4; ++r) {
        float x = acc[mi][nt][r] + bias;
        float s = x / (1.f + __expf(-x));
        Plds[w][mi * 16 + q * 4 + r][nt * 16 + c] = f2bf(s);
      }
  }
  f32x4 acc2[4][8];
#pragma unroll
  for (int mi = 0; mi < 4; ++mi)
#pragma unroll
    for (int nt = 0; nt < 8; ++nt) acc2[mi][nt] = (f32x4){0.f, 0.f, 0.f, 0.f};
#pragma unroll
  for (int kk = 0; kk < 4; ++kk) {
    s16x8 a2[4];
#pragma unroll
    for (int mi = 0; mi < 4; ++mi)
      a2[mi] = *reinterpret_cast<const s16x8*>(&Plds[w][mi * 16 + c][kk * 32 + q * 8]);
#pragma unroll
    for (int nt = 0; nt < 8; ++nt) {
      s16x8 b = *reinterpret_cast<const s16x8*>(wp + 36864 + (size_t)(kk * 8 + nt) * 512 + l * 8);
#pragma unroll
      for (int mi = 0; mi < 4; ++mi)
        acc2[mi][nt] = MFMA_BF16(a2[mi], b, acc2[mi][nt], 0, 0, 0);
    }
  }
#pragma unroll
  for (int nt = 0; nt < 8; ++nt) {
    float bias = b2[nt * 16 + c];
#pragma unroll
    for (int mi = 0; mi < 4; ++mi)
#pragma unroll
      for (int r = 0; r < 4; ++r) {
        int el = we + mi * 16 + q * 4 + r;
        if ((eb + el) < E) {
          int node = rows_s[el];
          unsafeAtomicAdd(&out[(size_t)node * 128 + nt * 16 + c],
                          acc2[mi][nt][r] + bias);
        }
      }
  }
}

extern "C" void kernel_launch(void* const* d_in, const int* in_sizes, int n_in,
                              void* d_out, int out_size, void* d_ws, size_t ws_size,
                              hipStream_t stream) {
  const float* h    = (const float*)d_in[0];
  const int*   ei   = (const int*)d_in[1];
  const float* bond = (const float*)d_in[2];
  const float* W1   = (const float*)d_in[3];
  const float* b1   = (const float*)d_in[4];
  const float* W2   = (const float*)d_in[5];
  const float* b2   = (const float*)d_in[6];
  float* out = (float*)d_out;
  char* ws = (char*)d_ws;

  const int E  = in_sizes[1] / 2;
  const int NN = in_sizes[0] / 128;

  // ws layout (bytes, 16-aligned)
  short* wp = (short*)ws;                                   // 131072
  size_t off_G    = 131072;
  size_t off_cnt  = off_G + (size_t)NN * 384;
  size_t off_par  = off_cnt + (((size_t)NN * 4 + 15) & ~15ull);
  size_t off_idx  = off_par + 4096;                         // rc (v11: E*4) or rce (v7: E*8)
  size_t off_bs   = off_idx + (((size_t)E * 4 + 15) & ~15ull);
  size_t need11   = off_bs + (size_t)E * 32;                // + sorted bf16 bond
  size_t need7    = off_idx + (size_t)E * 8;

  hipMemsetAsync(d_out, 0, (size_t)NN * 128 * sizeof(float), stream);
  prep_weights<<<26, 256, 0, stream>>>(W1, W2, wp);

  if (ws_size >= need11 && NN <= 65535) {
    short* Gs     = (short*)(ws + off_G);
    int*   cnt    = (int*)(ws + off_cnt);
    int*   par    = (int*)(ws + off_par);
    int*   rc     = (int*)(ws + off_idx);
    short* bond_s = (short*)(ws + off_bs);
    const int NB_G = (NN + 63) / 64;
    const int P    = (NN + 1023) / 1024;

    hipMemsetAsync(cnt, 0, (size_t)NN * 4, stream);
    k_gh<<<NB_G + NB_H, 256, 0, stream>>>(h, wp, Gs, ei, cnt, NN, NB_G, E);
    k_s1<<<P, 1024, 0, stream>>>(cnt, par, NN);
    k_s2<<<1, 1024, 0, stream>>>(par, P);
    k_s3<<<P, 1024, 0, stream>>>(cnt, par, NN);
    k_scatter8<<<2048, 256, 0, stream>>>(ei, cnt, rc, bond_s, bond, E);
    edge_mlp11<<<(E + 63) / 64, 256, 0, stream>>>(Gs, rc, bond_s, wp, b1, b2, out, E);
  } else if (ws_size >= need7 && NN <= 65535) {
    short* Gs   = (short*)(ws + off_G);
    int*   cnt  = (int*)(ws + off_cnt);
    int*   par  = (int*)(ws + off_par);
    int2*  rce  = (int2*)(ws + off_idx);
    const int NB_G = (NN + 63) / 64;
    const int P    = (NN + 1023) / 1024;

    hipMemsetAsync(cnt, 0, (size_t)NN * 4, stream);
    k_gh<<<NB_G + NB_H, 256, 0, stream>>>(h, wp, Gs, ei, cnt, NN, NB_G, E);
    k_s1<<<P, 1024, 0, stream>>>(cnt, par, NN);
    k_s2<<<1, 1024, 0, stream>>>(par, P);
    k_s3<<<P, 1024, 0, stream>>>(cnt, par, NN);
    k_scatter<<<2048, 256, 0, stream>>>(ei, cnt, rce, E);
    edge_mlp7<<<(E + 63) / 64, 256, 0, stream>>>(Gs, rce, bond, wp, b1, b2, out, E);
  } else {
    edge_mlp<<<(E + 255) / 256, 256, 0, stream>>>(h, ei, bond, wp, b1, b2, out, E);
  }
}